// Round 10
// baseline (169.092 us; speedup 1.0000x reference)
//
#include <hip/hip_runtime.h>
#include <hip/hip_fp16.h>
#include <cstddef>

#define Bc   32
#define Nc   512
#define Mc   512
#define DFc  64
#define BIGC 1.0e10f
#define LOG2E_F 1.4426950408889634f
#define LN2_F   0.6931471805599453f
#define SQRT_LOG2E_F 1.2011224087864498f

typedef unsigned int uint32;
typedef _Float16 f16x8 __attribute__((ext_vector_type(8)));
typedef float    f32x4 __attribute__((ext_vector_type(4)));

__device__ __forceinline__ float dpp_shr1(float oldv, float src) {
    return __int_as_float(__builtin_amdgcn_update_dpp(
        __float_as_int(oldv), __float_as_int(src), 0x138, 0xf, 0xf, false));
}
__device__ __forceinline__ float rl(float v, int lane) {
    return __int_as_float(__builtin_amdgcn_readlane(__float_as_int(v), lane));
}

// Bit-trick softmin, log2 domain, minus 127 (bias pre-folded into Dsk).
__device__ __forceinline__ float softmin3m(float a, float b, float c) {
    float mn = fminf(fminf(a, b), c);
    float mx = fmaxf(fmaxf(a, b), c);
    float md = __builtin_amdgcn_fmed3f(a, b, c);
    uint32 b1 = (uint32)fmaf(mn - mx, 8388608.0f, 1065353216.0f);
    uint32 b2 = (uint32)fmaf(mn - md, 8388608.0f, 1065353216.0f);
    float E = 1.0f + (__int_as_float(b1) + __int_as_float(b2));
    return fmaf((float)__float_as_uint(E), -1.1920929e-7f, mn);
}

// ---------------------------------------------------------------------------
// Kernel 1: MFMA distance computation. Staging/MFMA/epilogue = round 9.
// Output stage rewritten P-MAJOR for coalescing: wave w, iter it owns entry
// row j = 16w+it (p = 32J+j); lane l writes entry (p,l) iff t = 2j-l gives
// an owned col-pair (full 16B for 0<=t<=62; 8B straddle halves at t=-1 /
// t=63). Identical output bytes to round 9 (ownership formulas verified by
// substitution against the r9 lane-major straddle cases); each wave store is
// now one contiguous masked <=1024B segment instead of ~32 scattered 32B.
// ---------------------------------------------------------------------------
__global__ __launch_bounds__(256) void dist_kernel(
    const float* __restrict__ X, const float* __restrict__ Y,
    uint32* __restrict__ Dsk)
{
    __shared__ __align__(16) unsigned char SMEM[35840];
    unsigned short* XsH = (unsigned short*)SMEM;            // 16384 B
    unsigned short* YsH = (unsigned short*)(SMEM + 16384);  // 16384 B
    uint32* P  = (uint32*)SMEM;                             // 34816 B (aliases Xs/Ys)
    float* xx2 = (float*)(SMEM + 34816);                    // 512 B (survives P)
    float* yy2 = (float*)(SMEM + 35328);                    // 512 B

    const int b     = blockIdx.z;
    const int strip = blockIdx.y;
    const int J     = blockIdx.x;
    const int tid   = threadIdx.x;

    const float* Xg = X + ((size_t)b * Nc + strip * 128) * DFc;
    const float* Yg = Y + ((size_t)b * Mc + J * 128) * DFc;

#pragma unroll
    for (int it = 0; it < 8; ++it) {
        int e4 = it * 256 + tid;
        int n = e4 >> 4, k4 = (e4 & 15) * 4;
        float4 v = ((const float4*)Xg)[e4];
        float sx = v.x * SQRT_LOG2E_F, sy = v.y * SQRT_LOG2E_F;
        float sz = v.z * SQRT_LOG2E_F, sw = v.w * SQRT_LOG2E_F;
        __half2 h01 = __floats2half2_rn(sx, sy);
        __half2 h23 = __floats2half2_rn(sz, sw);
        int ho = (k4 + 8 * (n & 7)) & 63;
        uint2 u; u.x = *(uint32*)&h01; u.y = *(uint32*)&h23;
        *(uint2*)&XsH[n * 64 + ho] = u;
        float p = sx * sx + sy * sy + sz * sz + sw * sw;
        p += __shfl_xor(p, 1);
        p += __shfl_xor(p, 2);
        p += __shfl_xor(p, 4);
        p += __shfl_xor(p, 8);
        if ((tid & 15) == 0) xx2[n] = p + 127.0f;   // fold the +127 bias here
    }
#pragma unroll
    for (int it = 0; it < 8; ++it) {
        int e4 = it * 256 + tid;
        int m = e4 >> 4, k4 = (e4 & 15) * 4;
        float4 v = ((const float4*)Yg)[e4];
        float sx = v.x * SQRT_LOG2E_F, sy = v.y * SQRT_LOG2E_F;
        float sz = v.z * SQRT_LOG2E_F, sw = v.w * SQRT_LOG2E_F;
        __half2 h01 = __floats2half2_rn(sx, sy);
        __half2 h23 = __floats2half2_rn(sz, sw);
        int ho = (k4 + 8 * (m & 7)) & 63;
        uint2 u; u.x = *(uint32*)&h01; u.y = *(uint32*)&h23;
        *(uint2*)&YsH[m * 64 + ho] = u;
        float p = sx * sx + sy * sy + sz * sz + sw * sw;
        p += __shfl_xor(p, 1);
        p += __shfl_xor(p, 2);
        p += __shfl_xor(p, 4);
        p += __shfl_xor(p, 8);
        if ((tid & 15) == 0) yy2[m] = p;
    }
    __syncthreads();

    const int l  = tid & 63;
    const int w  = tid >> 6;     // wave 0..3: rows [32w, 32w+32)
    const int lr = l & 15;       // fragment row/col
    const int lk = l >> 4;       // fragment k-group

    f32x4 acc[2][8];
#pragma unroll
    for (int rt = 0; rt < 2; ++rt)
#pragma unroll
        for (int ct = 0; ct < 8; ++ct) {
            f32x4 z = {0.f, 0.f, 0.f, 0.f};
            acc[rt][ct] = z;
        }

#pragma unroll
    for (int ks = 0; ks < 2; ++ks) {
        f16x8 af[2], bf[8];
#pragma unroll
        for (int rt = 0; rt < 2; ++rt) {
            int row = w * 32 + rt * 16 + lr;
            int ho = (ks * 32 + lk * 8 + 8 * (row & 7)) & 63;
            af[rt] = *(const f16x8*)&XsH[row * 64 + ho];
        }
#pragma unroll
        for (int ct = 0; ct < 8; ++ct) {
            int col = ct * 16 + lr;
            int ho = (ks * 32 + lk * 8 + 8 * (col & 7)) & 63;
            bf[ct] = *(const f16x8*)&YsH[col * 64 + ho];
        }
#pragma unroll
        for (int rt = 0; rt < 2; ++rt)
#pragma unroll
            for (int ct = 0; ct < 8; ++ct)
                acc[rt][ct] = __builtin_amdgcn_mfma_f32_16x16x32_f16(
                    af[rt], bf[ct], acc[rt][ct], 0, 0, 0);
    }
    __syncthreads();   // Xs/Ys dead; P may now overwrite them

#pragma unroll
    for (int rt = 0; rt < 2; ++rt) {
        int rbase = w * 32 + rt * 16 + 4 * lk;
        f32x4 xr = *(const f32x4*)&xx2[rbase];
        int p0 = rbase >> 1;
#pragma unroll
        for (int ct = 0; ct < 8; ++ct) {
            int c = ct * 16 + lr;
            float yv = yy2[c];
            f32x4 a = acc[rt][ct];
            float d0 = xr[0] + yv - 2.0f * a[0];
            float d1 = xr[1] + yv - 2.0f * a[1];
            float d2 = xr[2] + yv - 2.0f * a[2];
            float d3 = xr[3] + yv - 2.0f * a[3];
            __half2 h0 = __floats2half2_rn(d0, d1);
            __half2 h1 = __floats2half2_rn(d2, d3);
            P[c * 67 + p0]     = *(uint32*)&h0;
            P[c * 67 + p0 + 1] = *(uint32*)&h1;
        }
    }
    __syncthreads();

    // ---- output stage: p-major coalesced writes ----
    {
        char* rbp = (char*)Dsk + (size_t)((b * 4 + strip) * 262144);
#pragma unroll 1
        for (int it = 0; it < 16; ++it) {
            const int j  = 16 * w + it;      // entry row within tile
            const int t  = 2 * j - l;        // owned col-pair offset
            char* dst = rbp + (32 * J + j) * 1024 + l * 16;
            if (0 <= t && t <= 62) {
                const int tc0 = 2 * t;       // local col = 4j - 2l
                uint32 p0 = P[(tc0    ) * 67 + l];
                uint32 p1 = P[(tc0 + 1) * 67 + l];
                uint32 p2 = P[(tc0 + 2) * 67 + l];
                uint32 p3 = P[(tc0 + 3) * 67 + l];
                uint4 v;
                v.x = (p0 & 0xffffu) | (p1 << 16);
                v.y = (p0 >> 16)     | (p1 & 0xffff0000u);
                v.z = (p2 & 0xffffu) | (p3 << 16);
                v.w = (p2 >> 16)     | (p3 & 0xffff0000u);
                *(uint4*)dst = v;
            } else if (t == 63) {            // right straddle: h0 only
                uint32 p0 = P[126 * 67 + l];
                uint32 p1 = P[127 * 67 + l];
                uint2 u;
                u.x = (p0 & 0xffffu) | (p1 << 16);
                u.y = (p0 >> 16)     | (p1 & 0xffff0000u);
                *(uint2*)dst = u;
            } else if (t == -1) {            // left straddle: h1 only
                uint32 p2 = P[0 * 67 + l];
                uint32 p3 = P[1 * 67 + l];
                uint2 u;
                u.x = (p2 & 0xffffu) | (p3 << 16);
                u.y = (p2 >> 16)     | (p3 & 0xffff0000u);
                *(uint2*)(dst + 8) = u;
            }
        }
    }
}

// ---------------------------------------------------------------------------
// Kernel 2: CONTINUOUS-SWEEP scan (VERBATIM round 9 — verified, fragile,
// do not touch). Each wave sweeps its 128-row strip across all 512 cols
// (col-pair c = slot - lane); lane skew paid once. Strip edges stream
// through a 64-entry LDS ring; write->read gap 17 slots, barrier every 16.
// ---------------------------------------------------------------------------
#define NSTEP(J_, dAw, dBw)                                                \
  {                                                                        \
    float u1 = dpp_shr1(evO[J_], pub1);                                    \
    float u2 = dpp_shr1(evE[J_], curB);                                    \
    float2 fA = __half22float2(*(const __half2*)&(dAw));                   \
    float2 fB = __half22float2(*(const __half2*)&(dBw));                   \
    float A1 = softmin3m(diagA, u1, curA) + fA.x;                          \
    float A2 = softmin3m(u1, u2, A1) + fA.y;                               \
    float B1 = softmin3m(curA, A1, curB) + fB.x;                           \
    float B2 = softmin3m(A1, A2, B1) + fB.y;                               \
    if (ls0 + (J_) == scap)                                                \
      capv = useB ? (useC2 ? B2 : B1) : (useC2 ? A2 : A1);                 \
    {                                                                      \
      int c = ls0 + (J_) - l;                                              \
      bool act = ((unsigned)c <= 255u);                                    \
      pub1  = act ? B1 : curB;   /* reads curB BEFORE update */            \
      curA  = act ? A2 : curA;                                             \
      curB  = act ? B2 : curB;                                             \
    }                                                                      \
    diagA = u2;                                                            \
    {                                                                      \
      float* wbs = pubEdge ? &ering[wl][(ls0 + (J_) + 1) & 63][0] : dumpw; \
      wbs[0] = B1; wbs[1] = B2;                                            \
    }                                                                      \
  }

__global__ __launch_bounds__(256) void scan_kernel(
    const uint32* __restrict__ Dsk,
    const int* __restrict__ X_len, const int* __restrict__ Y_len,
    float* __restrict__ out)
{
    __shared__ __align__(16) float ering[4][64][2];   // strip-edge rings
    __shared__ float dumpw[4];

    const int tid = threadIdx.x;
    const int l   = tid & 63;
    const int wl  = __builtin_amdgcn_readfirstlane(tid >> 6);  // strip 0..3
    const int bb  = blockIdx.x;

    const int xl = X_len[bb], yl = Y_len[bb];
    const int gcap = (xl - 1) >> 1;          // global row-pair of capture
    const int wcap = gcap >> 6;              // capture wave
    const int lcap = gcap & 63;              // capture lane
    const int useB  = (xl - 1) & 1;          // even xl -> B row
    const int useC2 = (yl - 1) & 1;          // even yl -> second col of pair
    const int ccap  = (yl - 1) >> 1;         // capture col-pair
    const int scapw = ccap + lcap;           // capture local slot (<= 318)
    const int scap  = (wl == wcap) ? scapw : -1000;
    const int blkmax = (80 * wcap + scapw) >> 4;

    const char* tbw = (const char*)Dsk + (size_t)((bb * 4 + wl) * 262144);
    const int voff = l * 16;
    const bool pubEdge = (l == 63) && (wl < 3);

    float curA = BIGC, curB = BIGC, pub1 = BIGC;
    float diagA = (wl == 0 && l == 0) ? 0.0f : BIGC;   // R[0][0] seed
    float capv = 0.0f;

    // Dsk prefetch ring: 8 uint4 = 16 slots ahead, linear addressing.
    uint4 dreg[8];
#pragma unroll
    for (int q = 0; q < 8; ++q)
        dreg[q] = *(const uint4*)(tbw + q * 1024 + voff);

    for (int blk = 0; blk <= blkmax; ++blk) {
        const int ls0 = blk * 16 - 80 * wl;
        if (wl <= wcap && 0 <= ls0 && ls0 <= 304) {
            // edge pairs for cols ls0..ls0+15 (all written >=1 barrier ago)
            float evO[16], evE[16];
            if (wl > 0) {
                const float* rb = &ering[wl - 1][ls0 & 63][0];
#pragma unroll
                for (int j = 0; j < 16; j += 2) {
                    float4 t = *(const float4*)(rb + 2 * j);
                    bool v0 = (ls0 + j)     <= 255;
                    bool v1 = (ls0 + j + 1) <= 255;
                    evO[j]     = v0 ? t.x : BIGC;
                    evE[j]     = v0 ? t.y : BIGC;
                    evO[j + 1] = v1 ? t.z : BIGC;
                    evE[j + 1] = v1 ? t.w : BIGC;
                }
            } else {
#pragma unroll
                for (int j = 0; j < 16; ++j) { evO[j] = BIGC; evE[j] = BIGC; }
            }
            const char* tbB = tbw + (size_t)(ls0 >> 1) * 1024 + voff;
#pragma unroll
            for (int q = 0; q < 8; ++q) {
                uint4 dc = dreg[q];
                dreg[q] = *(const uint4*)(tbB + (q + 8) * 1024);
                NSTEP(2 * q,     dc.x, dc.y)
                NSTEP(2 * q + 1, dc.z, dc.w)
            }
        }
        __syncthreads();
    }

    if (wl == wcap) {
        float o = rl(capv, lcap);
        if (l == 0) out[bb] = o * LN2_F;
    }
}

extern "C" void kernel_launch(void* const* d_in, const int* in_sizes, int n_in,
                              void* d_out, int out_size, void* d_ws, size_t ws_size,
                              hipStream_t stream)
{
    const float* X  = (const float*)d_in[0];
    const float* Y  = (const float*)d_in[1];
    const int*   xl = (const int*)d_in[2];
    const int*   yl = (const int*)d_in[3];
    float* out = (float*)d_out;
    uint32* Dsk = (uint32*)d_ws;   // 32 b * 4 strips * 256 KB = 32 MB

    dist_kernel<<<dim3(4, 4, Bc), 256, 0, stream>>>(X, Y, Dsk);
    scan_kernel<<<Bc, 256, 0, stream>>>(Dsk, xl, yl, out);
}